// Round 6
// baseline (67867.297 us; speedup 1.0000x reference)
//
#include <hip/hip_runtime.h>
#include <hip/hip_bf16.h>
#include <math.h>

typedef unsigned short u16;
typedef unsigned int   u32;
typedef __attribute__((ext_vector_type(8))) short short8;
typedef __attribute__((ext_vector_type(4))) float float4v;

#define BB 64
#define SS 512

// bf16 helpers (RNE)
__device__ __forceinline__ u16 f2b(float f) {
    u32 x = __float_as_uint(f);
    u32 r = (x + 0x7fffu + ((x >> 16) & 1u)) >> 16;
    return (u16)r;
}
__device__ __forceinline__ float b2f(u32 lo16) { return __uint_as_float(lo16 << 16); }
__device__ __forceinline__ float b2fh(u32 v)   { return __uint_as_float(v & 0xffff0000u); }

// ---------------------------------------------------------------------------
__global__ __launch_bounds__(256) void zero_kernel(float* __restrict__ p, int n) {
    int i = blockIdx.x * 256 + threadIdx.x;
    if (i < n) p[i] = 0.f;
}

// ---------------------------------------------------------------------------
__global__ __launch_bounds__(256) void pe_kernel(float* __restrict__ pe) {
    int s = blockIdx.x, j = threadIdx.x;
    float ang = (float)s * powf(10000.0f, -(2.0f * (float)j) / 512.0f);
    pe[s * 512 + 2 * j]     = sinf(ang);
    pe[s * 512 + 2 * j + 1] = cosf(ang);
}

// ---------------------------------------------------------------------------
// fp32 [R][C] -> bf16 [C][R]
// ---------------------------------------------------------------------------
__global__ __launch_bounds__(256) void transp_w(const float* __restrict__ in,
                                                u16* __restrict__ out, int R, int C) {
    __shared__ float t[64][65];
    int r0 = blockIdx.x * 64, c0 = blockIdx.y * 64;
    int tid = threadIdx.x;
    int lr = tid >> 4, lc4 = (tid & 15) * 4;
#pragma unroll
    for (int i = 0; i < 4; i++) {
        int r = lr + i * 16;
        float4 v = *(const float4*)(in + (long)(r0 + r) * C + c0 + lc4);
        t[r][lc4] = v.x; t[r][lc4 + 1] = v.y; t[r][lc4 + 2] = v.z; t[r][lc4 + 3] = v.w;
    }
    __syncthreads();
#pragma unroll
    for (int i = 0; i < 4; i++) {
        int c = lr + i * 16;
        u32 lo = (u32)f2b(t[lc4][c])     | ((u32)f2b(t[lc4 + 1][c]) << 16);
        u32 hi = (u32)f2b(t[lc4 + 2][c]) | ((u32)f2b(t[lc4 + 3][c]) << 16);
        uint2 pk; pk.x = lo; pk.y = hi;
        *(uint2*)(out + (long)(c0 + c) * R + r0 + lc4) = pk;
    }
}

// ---------------------------------------------------------------------------
__global__ __launch_bounds__(256) void cvt_bf16(const float* __restrict__ in,
                                                u16* __restrict__ out, long n) {
    long i = (long)blockIdx.x * 256 + threadIdx.x;
    if (i < n) out[i] = f2b(in[i]);
}

// ---------------------------------------------------------------------------
// bf16 [nb][R][C] -> out[b][c][r] with element strides
// ---------------------------------------------------------------------------
__global__ __launch_bounds__(256) void transp_b(const u16* __restrict__ in,
                                                u16* __restrict__ out,
                                                int R, int C, long sbin, long sb, long sc) {
    __shared__ u32 t[64][65];
    int bz = blockIdx.z;
    in += (long)bz * sbin;
    int r0 = blockIdx.x * 64, c0 = blockIdx.y * 64;
    int tid = threadIdx.x;
    int lr = tid >> 4, lc4 = (tid & 15) * 4;
#pragma unroll
    for (int i = 0; i < 4; i++) {
        int r = lr + i * 16;
        uint2 v = *(const uint2*)(in + (long)(r0 + r) * C + c0 + lc4);
        t[r][lc4] = v.x & 0xffffu; t[r][lc4 + 1] = v.x >> 16;
        t[r][lc4 + 2] = v.y & 0xffffu; t[r][lc4 + 3] = v.y >> 16;
    }
    __syncthreads();
#pragma unroll
    for (int i = 0; i < 4; i++) {
        int c = lr + i * 16;
        uint2 pk;
        pk.x = t[lc4][c] | (t[lc4 + 1][c] << 16);
        pk.y = t[lc4 + 2][c] | (t[lc4 + 3][c] << 16);
        *(uint2*)(out + (long)bz * sb + (long)(c0 + c) * sc + r0 + lc4) = pk;
    }
}

// ---------------------------------------------------------------------------
__global__ __launch_bounds__(256) void embed_kernel(
    const int* __restrict__ cate, const float* __restrict__ cont,
    const float* __restrict__ emb, const float* __restrict__ Wc,
    const float* __restrict__ bc, u16* __restrict__ xc, int gbase)
{
    long bs = (long)gbase + blockIdx.x;
    long r  = blockIdx.x;
    __shared__ float cf[6];
    if (threadIdx.x < 6) cf[threadIdx.x] = cont[bs * 6 + threadIdx.x];
    __syncthreads();
    for (int h = threadIdx.x; h < 1024; h += 256) {
        float v;
        if (h < 512) {
            int c = h >> 7, e = h & 127;
            int idx = cate[bs * 4 + c];
            v = emb[((long)c * 1000 + idx) * 128 + e];
        } else {
            int hh = h - 512;
            v = bc[hh];
#pragma unroll
            for (int f = 0; f < 6; f++) v += cf[f] * Wc[f * 512 + hh];
        }
        xc[r * 1024 + h] = f2b(v);
    }
}

// ---------------------------------------------------------------------------
// bf16 MFMA NT GEMM (validated: absmax 0.0)
// ---------------------------------------------------------------------------
__global__ __launch_bounds__(256) void gemm_nt(
    const u16* __restrict__ A, const u16* __restrict__ B, void* __restrict__ Cv,
    int K, int lda, int ldb, int ldc,
    long sA, long sB, long sC,
    const float* __restrict__ bias, const float* __restrict__ pe,
    float alpha, int outBf16)
{
    __shared__ u16 As[128][40];
    __shared__ u16 Bs[128][40];

    A += (long)blockIdx.z * sA;
    B += (long)blockIdx.z * sB;
    int m0 = blockIdx.y * 128, n0 = blockIdx.x * 128;
    int tid = threadIdx.x;
    int lane = tid & 63, wid = tid >> 6;
    int wm = (wid >> 1) * 64, wn = (wid & 1) * 64;
    int mrow = lane & 15, q8 = (lane >> 4) * 8;

    float4v acc[4][4];
#pragma unroll
    for (int i = 0; i < 4; i++)
#pragma unroll
        for (int j = 0; j < 4; j++) { float4v z = {0.f, 0.f, 0.f, 0.f}; acc[i][j] = z; }

    for (int k0 = 0; k0 < K; k0 += 32) {
        {
            int r = tid >> 2, sg = tid & 3;
            *(short8*)&As[r][sg * 8] = *(const short8*)(A + (long)(m0 + r) * lda + k0 + sg * 8);
            *(short8*)&Bs[r][sg * 8] = *(const short8*)(B + (long)(n0 + r) * ldb + k0 + sg * 8);
            r = (tid + 256) >> 2;
            *(short8*)&As[r][sg * 8] = *(const short8*)(A + (long)(m0 + r) * lda + k0 + sg * 8);
            *(short8*)&Bs[r][sg * 8] = *(const short8*)(B + (long)(n0 + r) * ldb + k0 + sg * 8);
        }
        __syncthreads();
        short8 af[4], bfr[4];
#pragma unroll
        for (int t = 0; t < 4; t++) {
            af[t]  = *(const short8*)&As[wm + t * 16 + mrow][q8];
            bfr[t] = *(const short8*)&Bs[wn + t * 16 + mrow][q8];
        }
#pragma unroll
        for (int i = 0; i < 4; i++)
#pragma unroll
            for (int j = 0; j < 4; j++)
                acc[i][j] = __builtin_amdgcn_mfma_f32_16x16x32_bf16(af[i], bfr[j], acc[i][j], 0, 0, 0);
        __syncthreads();
    }

    int col = lane & 15, quad = lane >> 4;
    u16*  Cb = (u16*)Cv  + (outBf16 ? (long)blockIdx.z * sC : 0);
    float* Cf = (float*)Cv + (outBf16 ? 0 : (long)blockIdx.z * sC);
#pragma unroll
    for (int i = 0; i < 4; i++)
#pragma unroll
        for (int j = 0; j < 4; j++) {
#pragma unroll
            for (int rr = 0; rr < 4; rr++) {
                int gm = m0 + wm + i * 16 + quad * 4 + rr;
                int gn = n0 + wn + j * 16 + col;
                float v = acc[i][j][rr] * alpha;
                if (bias) v += bias[gn];
                if (pe)   v += pe[(long)(gm & 511) * 512 + gn];
                if (outBf16) Cb[(long)gm * ldc + gn] = f2b(v);
                else         Cf[(long)gm * ldc + gn] = v;
            }
        }
}

// ---------------------------------------------------------------------------
// Softmax over QUERY axis fp32 -> bf16
// ---------------------------------------------------------------------------
__global__ __launch_bounds__(64) void softmax_q(const float* __restrict__ S,
                                                u16* __restrict__ P) {
    int b = blockIdx.x;
    int k = blockIdx.y * 64 + threadIdx.x;
    const float* p = S + (long)b * 262144 + k;
    u16* o = P + (long)b * 262144 + k;
    float m = -1e30f;
    for (int q = 0; q < 512; q++) m = fmaxf(m, p[(long)q * 512]);
    float sum = 0.f;
    for (int q = 0; q < 512; q++) sum += expf(p[(long)q * 512] - m);
    float inv = 1.f / sum;
    for (int q = 0; q < 512; q++) o[(long)q * 512] = f2b(expf(p[(long)q * 512] - m) * inv);
}

// ---------------------------------------------------------------------------
// Cooperative persistent GRU, 128-step segment. fp32 Wh in LDS, fp32 h.
// Grid 256 = 8 batch-groups(8 batches) x 32 unit-slices(16 units).
// Barrier: per-block arrival flags (64B-padded) + master fan-in + go word.
// No atomic RMW on hot lines (previous single-counter barrier cost ~40us/step).
// ---------------------------------------------------------------------------
__global__ __launch_bounds__(256, 1) void gru_coop(
    const float* __restrict__ gi,     // [128][64][1536] fp32 (includes bi)
    const float* __restrict__ Wh_l,   // [1536][512] fp32
    const float* __restrict__ bh_l,   // [1536]
    u16* __restrict__ seq_out,        // [512*64][512] bf16
    float* __restrict__ hg,           // [2][64][512] fp32
    u32* __restrict__ flags,          // [256] 64B-padded arrival flags
    u32* __restrict__ go,             // broadcast word
    int s0, int sync_base)
{
    __shared__ float whl[48 * 529];
    __shared__ float hl[8 * 648];        // stride 648, skew col + (col/32)*9
    __shared__ float psum[16][8][16][3];

    int blk = blockIdx.x;
    int grp = blk >> 5;          // 0..7  batch group (8 batches)
    int ubk = blk & 31;          // 0..31 unit slice (16 units)
    int ub  = ubk * 16;
    int tid = threadIdx.x;
    int ut  = tid & 15;
    int q   = tid >> 4;          // 0..15 (32-col slice)

    // --- Wh slice -> LDS fp32, once per segment ---
    for (int i = tid; i < 48 * 128; i += 256) {
        int r  = i >> 7;                 // 0..47 = gate*16 + unit
        int c4 = (i & 127) << 2;
        int g  = r >> 4, u = r & 15;
        float4 f = *(const float4*)(Wh_l + ((long)(g * 512 + ub + u)) * 512 + c4);
        int p = r * 529 + c4 + (c4 >> 5);
        whl[p] = f.x; whl[p + 1] = f.y; whl[p + 2] = f.z; whl[p + 3] = f.w;
    }

    // gate-phase constants (threads 0..127: btg = tid>>4 in 0..7, unit ut)
    float bhv0 = 0.f, bhv1 = 0.f, bhv2 = 0.f;
    int btg = tid >> 4;
    if (tid < 128) {
        bhv0 = bh_l[ub + ut];
        bhv1 = bh_l[512 + ub + ut];
        bhv2 = bh_l[1024 + ub + ut];
    }

    // --- init h ---
    if (s0 == 0) {
        for (int i = tid; i < 8 * 648; i += 256) hl[i] = 0.f;
    } else {
        const float* src = hg + (long)(s0 & 1) * 32768 + grp * 8 * 512;
        for (int i = tid; i < 1024; i += 256) {
            int b = i >> 7, c4 = (i & 127) << 2;
            float4 f = *(const float4*)(src + b * 512 + c4);
            *(float4*)&hl[b * 648 + c4 + (c4 >> 5) * 9] = f;
        }
    }
    __syncthreads();

    const int qoff_h = q * 41;           // q*32 + 9*q: conflict-free q-spread
    const int w0off = (ut) * 529 + q * 33;
    const int w1off = (16 + ut) * 529 + q * 33;
    const int w2off = (32 + ut) * 529 + q * 33;

    for (int sl = 0; sl < 128; sl++) {
        int gstep = s0 + sl;

        float acc0[8], acc1[8], acc2[8];
#pragma unroll
        for (int b = 0; b < 8; b++) { acc0[b] = 0.f; acc1[b] = 0.f; acc2[b] = 0.f; }

#pragma unroll
        for (int c8 = 0; c8 < 8; c8++) {
            int hc = qoff_h + c8 * 4;
            float4 hb[8];
#pragma unroll
            for (int b = 0; b < 8; b++) hb[b] = *(const float4*)&hl[b * 648 + hc];
            int wc = c8 * 4;
            float a0 = whl[w0off + wc], a1 = whl[w0off + wc + 1],
                  a2 = whl[w0off + wc + 2], a3 = whl[w0off + wc + 3];
            float b0 = whl[w1off + wc], b1 = whl[w1off + wc + 1],
                  b2 = whl[w1off + wc + 2], b3 = whl[w1off + wc + 3];
            float c0 = whl[w2off + wc], c1 = whl[w2off + wc + 1],
                  c2 = whl[w2off + wc + 2], c3 = whl[w2off + wc + 3];
#pragma unroll
            for (int b = 0; b < 8; b++) {
                float4 h = hb[b];
                acc0[b] += a0 * h.x + a1 * h.y + a2 * h.z + a3 * h.w;
                acc1[b] += b0 * h.x + b1 * h.y + b2 * h.z + b3 * h.w;
                acc2[b] += c0 * h.x + c1 * h.y + c2 * h.z + c3 * h.w;
            }
        }
#pragma unroll
        for (int b = 0; b < 8; b++) {
            psum[q][b][ut][0] = acc0[b];
            psum[q][b][ut][1] = acc1[b];
            psum[q][b][ut][2] = acc2[b];
        }
        __syncthreads();

        // --- gate math on 128 threads ---
        if (tid < 128) {
            float sr = 0.f, sz = 0.f, sn = 0.f;
#pragma unroll
            for (int qq = 0; qq < 16; qq++) {
                sr += psum[qq][btg][ut][0];
                sz += psum[qq][btg][ut][1];
                sn += psum[qq][btg][ut][2];
            }
            const float* g = gi + ((long)sl * 64 + grp * 8 + btg) * 1536;
            int col = ub + ut;
            float ir = g[col], iz = g[512 + col], inn = g[1024 + col];
            float r  = 1.f / (1.f + expf(-(ir + sr + bhv0)));
            float zg = 1.f / (1.f + expf(-(iz + sz + bhv1)));
            float n  = tanhf(inn + r * (sn + bhv2));
            float hprev = hl[btg * 648 + col + (col >> 5) * 9];
            float hn = (1.f - zg) * n + zg * hprev;
            hg[(long)((gstep + 1) & 1) * 32768 + (grp * 8 + btg) * 512 + col] = hn;
            seq_out[((long)gstep * 64 + grp * 8 + btg) * 512 + col] = f2b(hn);
        }

        // --- flag/fan-in device barrier (no RMW) ---
        u32 target = (u32)(sync_base + sl + 1);
        __threadfence();
        __syncthreads();
        if (tid == 0)
            __hip_atomic_store(flags + blk * 16, target, __ATOMIC_RELEASE,
                               __HIP_MEMORY_SCOPE_AGENT);
        if (blk == 0) {
            u32* f = flags + tid * 16;
            while (__hip_atomic_load(f, __ATOMIC_ACQUIRE, __HIP_MEMORY_SCOPE_AGENT) < target)
                __builtin_amdgcn_s_sleep(1);
            __syncthreads();
            if (tid == 0)
                __hip_atomic_store(go, target, __ATOMIC_RELEASE, __HIP_MEMORY_SCOPE_AGENT);
        }
        if (tid == 0) {
            while (__hip_atomic_load(go, __ATOMIC_ACQUIRE, __HIP_MEMORY_SCOPE_AGENT) < target)
                __builtin_amdgcn_s_sleep(1);
        }
        __syncthreads();
        __threadfence();

        // --- reload h (our 8 batches) ---
        const float* src = hg + (long)((gstep + 1) & 1) * 32768 + grp * 8 * 512;
        for (int i = tid; i < 1024; i += 256) {
            int b = i >> 7, c4 = (i & 127) << 2;
            float4 f = *(const float4*)(src + b * 512 + c4);
            *(float4*)&hl[b * 648 + c4 + (c4 >> 5) * 9] = f;
        }
        __syncthreads();
    }
}

// ---------------------------------------------------------------------------
__global__ __launch_bounds__(256) void final_kernel(
    const u16* __restrict__ h2, const float* __restrict__ Wf,
    const float* __restrict__ bfin, float* __restrict__ out)
{
    int w = blockIdx.x * 4 + (threadIdx.x >> 6);
    int lane = threadIdx.x & 63;
    const u16* row = h2 + (long)w * 512;
    uint4 hv = *(const uint4*)(row + lane * 8);
    float4 w0 = *(const float4*)(Wf + lane * 8);
    float4 w1 = *(const float4*)(Wf + lane * 8 + 4);
    float sum = b2f(hv.x & 0xffffu) * w0.x + b2fh(hv.x) * w0.y
              + b2f(hv.y & 0xffffu) * w0.z + b2fh(hv.y) * w0.w
              + b2f(hv.z & 0xffffu) * w1.x + b2fh(hv.z) * w1.y
              + b2f(hv.w & 0xffffu) * w1.z + b2fh(hv.w) * w1.w;
#pragma unroll
    for (int off = 32; off > 0; off >>= 1) sum += __shfl_down(sum, off, 64);
    if (lane == 0) {
        int s = w >> 6, b = w & 63;
        out[(long)b * 512 + s] = 1.f / (1.f + expf(-(sum + bfin[0])));
    }
}

// ---------------------------------------------------------------------------
// Launcher — workspace ~166.5 MB
// ---------------------------------------------------------------------------
extern "C" void kernel_launch(void* const* d_in, const int* in_sizes, int n_in,
                              void* d_out, int out_size, void* d_ws, size_t ws_size,
                              hipStream_t stream) {
    const int*   cate  = (const int*)  d_in[0];
    const float* cont  = (const float*)d_in[1];
    const float* emb   = (const float*)d_in[4];
    const float* Wc    = (const float*)d_in[5];
    const float* bc    = (const float*)d_in[6];
    const float* Wcomb = (const float*)d_in[7];
    const float* bcomb = (const float*)d_in[8];
    const float* Wq    = (const float*)d_in[9];
    const float* Wk    = (const float*)d_in[10];
    const float* Wv    = (const float*)d_in[11];
    const float* Wi    = (const float*)d_in[12];
    const float* Wh    = (const float*)d_in[13];
    const float* bi    = (const float*)d_in[14];
    const float* bh    = (const float*)d_in[15];
    const float* Wf    = (const float*)d_in[16];
    const float* bfin  = (const float*)d_in[17];
    float* out = (float*)d_out;
    char* ws = (char*)d_ws;

    u16*   zp    = (u16*)(ws + 0);
    u16*   h2bf  = (u16*)(ws + 0);
    u16*   h1bf  = (u16*)(ws + 33554432);
    float* gi    = (float*)(ws + 67108864);   // 50.3 MB, aliases xbf
    u16*   xbf   = (u16*)(ws + 67108864);
    u16*   Qg    = (u16*)(ws + 117440512);
    u16*   Kg    = (u16*)(ws + 121634816);
    u16*   Vg    = (u16*)(ws + 125829120);
    u16*   Vt    = (u16*)(ws + 130023424);
    float* Sg    = (float*)(ws + 134217728);
    u16*   Pg    = (u16*)(ws + 142606336);
    u16*   zT    = (u16*)(ws + 146800640);
    u16*   xc    = (u16*)(ws + 150994944);
    u16*   WcombT= (u16*)(ws + 159383552);
    u16*   WqT   = (u16*)(ws + 160432128);
    u16*   WkT   = (u16*)(ws + 160956416);
    u16*   WvT   = (u16*)(ws + 161480704);
    u16*   WiB   = (u16*)(ws + 162004992);
    float* pe    = (float*)(ws + 165150720);
    float* hg    = (float*)(ws + 166199296);  // [2][64][512] fp32
    u32*   flags = (u32*)  (ws + 166461440);  // [256] 64B-padded + go
    u32*   go    = flags + 256 * 16;

    zero_kernel<<<17, 256, 0, stream>>>((float*)flags, 256 * 16 + 16);
    transp_w<<<dim3(16, 8), 256, 0, stream>>>(Wcomb, WcombT, 1024, 512);
    transp_w<<<dim3(8, 8),  256, 0, stream>>>(Wq, WqT, 512, 512);
    transp_w<<<dim3(8, 8),  256, 0, stream>>>(Wk, WkT, 512, 512);
    transp_w<<<dim3(8, 8),  256, 0, stream>>>(Wv, WvT, 512, 512);
    cvt_bf16<<<6144, 256, 0, stream>>>(Wi, WiB, 2L * 1536 * 512);
    pe_kernel<<<512, 256, 0, stream>>>(pe);

    // phase 1
    for (int g = 0; g < 8; g++) {
        embed_kernel<<<4096, 256, 0, stream>>>(cate, cont, emb, Wc, bc, xc, g * 4096);
        gemm_nt<<<dim3(4, 32, 1), 256, 0, stream>>>(
            xc, WcombT, xbf + (long)g * 4096 * 512, 1024, 1024, 1024, 512,
            0, 0, 0, bcomb, pe, 1.f, 1);
    }

    // phase 2
    for (int g = 0; g < 8; g++) {
        const u16* xg = xbf + (long)g * 8 * 512 * 512;
        gemm_nt<<<dim3(4, 32, 1), 256, 0, stream>>>(xg, WqT, Qg, 512, 512, 512, 512,
                                                    0, 0, 0, nullptr, nullptr, 1.f, 1);
        gemm_nt<<<dim3(4, 32, 1), 256, 0, stream>>>(xg, WkT, Kg, 512, 512, 512, 512,
                                                    0, 0, 0, nullptr, nullptr, 1.f, 1);
        gemm_nt<<<dim3(4, 32, 1), 256, 0, stream>>>(xg, WvT, Vg, 512, 512, 512, 512,
                                                    0, 0, 0, nullptr, nullptr, 1.f, 1);
        transp_b<<<dim3(8, 8, 8), 256, 0, stream>>>(Vg, Vt, 512, 512, 262144, 262144, 512);
        gemm_nt<<<dim3(4, 4, 8), 256, 0, stream>>>(Qg, Kg, Sg, 512, 512, 512, 512,
                                                   262144, 262144, 262144, nullptr, nullptr,
                                                   0.04419417382415922f, 0);
        softmax_q<<<dim3(8, 8), 64, 0, stream>>>(Sg, Pg);
        gemm_nt<<<dim3(4, 4, 8), 256, 0, stream>>>(Vt, Pg, zT, 512, 512, 512, 512,
                                                   262144, 262144, 262144, nullptr, nullptr,
                                                   1.f, 1);
        transp_b<<<dim3(8, 8, 8), 256, 0, stream>>>(zT, zp + (long)g * 8 * 512,
                                                    512, 512, 262144, 512, 32768);
    }

    // phase 3: GRU
    for (int l = 0; l < 2; l++) {
        const u16* Aseq = (l == 0) ? zp : h1bf;
        u16* seqOut = (l == 0) ? h1bf : h2bf;
        const u16* WiL = WiB + (long)l * 1536 * 512;
        const float* WhL = Wh + (long)l * 1536 * 512;
        const float* biL = bi + (long)l * 1536;
        const float* bhL = bh + (long)l * 1536;
        for (int seg = 0; seg < 4; seg++) {
            gemm_nt<<<dim3(12, 64, 1), 256, 0, stream>>>(
                Aseq + (long)seg * 128 * 64 * 512, WiL, gi, 512, 512, 512, 1536,
                0, 0, 0, biL, nullptr, 1.f, 0);
            const float* giP = gi;
            u16* soP = seqOut;
            int s0v = seg * 128;
            int sbv = (l * 4 + seg) * 128;
            void* args[] = { (void*)&giP, (void*)&WhL, (void*)&bhL, (void*)&soP,
                             (void*)&hg, (void*)&flags, (void*)&go,
                             (void*)&s0v, (void*)&sbv };
            hipLaunchCooperativeKernel((void*)gru_coop, dim3(256), dim3(256),
                                       args, 0, stream);
        }
    }

    final_kernel<<<8192, 256, 0, stream>>>(h2bf, Wf, bfin, out);
}

// Round 7
// 26031.641 us; speedup vs baseline: 2.6071x; 2.6071x over previous
//
#include <hip/hip_runtime.h>
#include <hip/hip_bf16.h>
#include <math.h>

typedef unsigned short u16;
typedef unsigned int   u32;
typedef __attribute__((ext_vector_type(8))) short short8;
typedef __attribute__((ext_vector_type(4))) float float4v;

#define BB 64
#define SS 512

// bf16 helpers (RNE)
__device__ __forceinline__ u16 f2b(float f) {
    u32 x = __float_as_uint(f);
    u32 r = (x + 0x7fffu + ((x >> 16) & 1u)) >> 16;
    return (u16)r;
}
__device__ __forceinline__ float b2f(u32 lo16) { return __uint_as_float(lo16 << 16); }
__device__ __forceinline__ float b2fh(u32 v)   { return __uint_as_float(v & 0xffff0000u); }

// ---------------------------------------------------------------------------
__global__ __launch_bounds__(256) void pe_kernel(float* __restrict__ pe) {
    int s = blockIdx.x, j = threadIdx.x;
    float ang = (float)s * powf(10000.0f, -(2.0f * (float)j) / 512.0f);
    pe[s * 512 + 2 * j]     = sinf(ang);
    pe[s * 512 + 2 * j + 1] = cosf(ang);
}

// ---------------------------------------------------------------------------
// fp32 [R][C] -> bf16 [C][R]
// ---------------------------------------------------------------------------
__global__ __launch_bounds__(256) void transp_w(const float* __restrict__ in,
                                                u16* __restrict__ out, int R, int C) {
    __shared__ float t[64][65];
    int r0 = blockIdx.x * 64, c0 = blockIdx.y * 64;
    int tid = threadIdx.x;
    int lr = tid >> 4, lc4 = (tid & 15) * 4;
#pragma unroll
    for (int i = 0; i < 4; i++) {
        int r = lr + i * 16;
        float4 v = *(const float4*)(in + (long)(r0 + r) * C + c0 + lc4);
        t[r][lc4] = v.x; t[r][lc4 + 1] = v.y; t[r][lc4 + 2] = v.z; t[r][lc4 + 3] = v.w;
    }
    __syncthreads();
#pragma unroll
    for (int i = 0; i < 4; i++) {
        int c = lr + i * 16;
        u32 lo = (u32)f2b(t[lc4][c])     | ((u32)f2b(t[lc4 + 1][c]) << 16);
        u32 hi = (u32)f2b(t[lc4 + 2][c]) | ((u32)f2b(t[lc4 + 3][c]) << 16);
        uint2 pk; pk.x = lo; pk.y = hi;
        *(uint2*)(out + (long)(c0 + c) * R + r0 + lc4) = pk;
    }
}

// ---------------------------------------------------------------------------
__global__ __launch_bounds__(256) void cvt_bf16(const float* __restrict__ in,
                                                u16* __restrict__ out, long n) {
    long i = (long)blockIdx.x * 256 + threadIdx.x;
    if (i < n) out[i] = f2b(in[i]);
}

// ---------------------------------------------------------------------------
// Wh [2][1536][512] fp32 -> WT4 [2][128][1536][4] fp32  (k-blocked transpose)
// ---------------------------------------------------------------------------
__global__ __launch_bounds__(256) void wh_transp(const float* __restrict__ Wh,
                                                 float* __restrict__ WT4) {
    long i = (long)blockIdx.x * 256 + threadIdx.x;    // < 2*786432
    if (i >= 2L * 786432) return;
    long l = i / 786432;
    long r = i % 786432;
    int k4 = (int)(r / 6144);
    int rem = (int)(r % 6144);
    int j = rem >> 2, kk = rem & 3;
    WT4[i] = Wh[l * 786432 + (long)j * 512 + k4 * 4 + kk];
}

// ---------------------------------------------------------------------------
// bf16 [nb][R][C] -> out[b][c][r] with element strides
// ---------------------------------------------------------------------------
__global__ __launch_bounds__(256) void transp_b(const u16* __restrict__ in,
                                                u16* __restrict__ out,
                                                int R, int C, long sbin, long sb, long sc) {
    __shared__ u32 t[64][65];
    int bz = blockIdx.z;
    in += (long)bz * sbin;
    int r0 = blockIdx.x * 64, c0 = blockIdx.y * 64;
    int tid = threadIdx.x;
    int lr = tid >> 4, lc4 = (tid & 15) * 4;
#pragma unroll
    for (int i = 0; i < 4; i++) {
        int r = lr + i * 16;
        uint2 v = *(const uint2*)(in + (long)(r0 + r) * C + c0 + lc4);
        t[r][lc4] = v.x & 0xffffu; t[r][lc4 + 1] = v.x >> 16;
        t[r][lc4 + 2] = v.y & 0xffffu; t[r][lc4 + 3] = v.y >> 16;
    }
    __syncthreads();
#pragma unroll
    for (int i = 0; i < 4; i++) {
        int c = lr + i * 16;
        uint2 pk;
        pk.x = t[lc4][c] | (t[lc4 + 1][c] << 16);
        pk.y = t[lc4 + 2][c] | (t[lc4 + 3][c] << 16);
        *(uint2*)(out + (long)bz * sb + (long)(c0 + c) * sc + r0 + lc4) = pk;
    }
}

// ---------------------------------------------------------------------------
__global__ __launch_bounds__(256) void embed_kernel(
    const int* __restrict__ cate, const float* __restrict__ cont,
    const float* __restrict__ emb, const float* __restrict__ Wc,
    const float* __restrict__ bc, u16* __restrict__ xc, int gbase)
{
    long bs = (long)gbase + blockIdx.x;
    long r  = blockIdx.x;
    __shared__ float cf[6];
    if (threadIdx.x < 6) cf[threadIdx.x] = cont[bs * 6 + threadIdx.x];
    __syncthreads();
    for (int h = threadIdx.x; h < 1024; h += 256) {
        float v;
        if (h < 512) {
            int c = h >> 7, e = h & 127;
            int idx = cate[bs * 4 + c];
            v = emb[((long)c * 1000 + idx) * 128 + e];
        } else {
            int hh = h - 512;
            v = bc[hh];
#pragma unroll
            for (int f = 0; f < 6; f++) v += cf[f] * Wc[f * 512 + hh];
        }
        xc[r * 1024 + h] = f2b(v);
    }
}

// ---------------------------------------------------------------------------
// bf16 MFMA NT GEMM (validated: absmax 0.0)
// ---------------------------------------------------------------------------
__global__ __launch_bounds__(256) void gemm_nt(
    const u16* __restrict__ A, const u16* __restrict__ B, void* __restrict__ Cv,
    int K, int lda, int ldb, int ldc,
    long sA, long sB, long sC,
    const float* __restrict__ bias, const float* __restrict__ pe,
    float alpha, int outBf16)
{
    __shared__ u16 As[128][40];
    __shared__ u16 Bs[128][40];

    A += (long)blockIdx.z * sA;
    B += (long)blockIdx.z * sB;
    int m0 = blockIdx.y * 128, n0 = blockIdx.x * 128;
    int tid = threadIdx.x;
    int lane = tid & 63, wid = tid >> 6;
    int wm = (wid >> 1) * 64, wn = (wid & 1) * 64;
    int mrow = lane & 15, q8 = (lane >> 4) * 8;

    float4v acc[4][4];
#pragma unroll
    for (int i = 0; i < 4; i++)
#pragma unroll
        for (int j = 0; j < 4; j++) { float4v z = {0.f, 0.f, 0.f, 0.f}; acc[i][j] = z; }

    for (int k0 = 0; k0 < K; k0 += 32) {
        {
            int r = tid >> 2, sg = tid & 3;
            *(short8*)&As[r][sg * 8] = *(const short8*)(A + (long)(m0 + r) * lda + k0 + sg * 8);
            *(short8*)&Bs[r][sg * 8] = *(const short8*)(B + (long)(n0 + r) * ldb + k0 + sg * 8);
            r = (tid + 256) >> 2;
            *(short8*)&As[r][sg * 8] = *(const short8*)(A + (long)(m0 + r) * lda + k0 + sg * 8);
            *(short8*)&Bs[r][sg * 8] = *(const short8*)(B + (long)(n0 + r) * ldb + k0 + sg * 8);
        }
        __syncthreads();
        short8 af[4], bfr[4];
#pragma unroll
        for (int t = 0; t < 4; t++) {
            af[t]  = *(const short8*)&As[wm + t * 16 + mrow][q8];
            bfr[t] = *(const short8*)&Bs[wn + t * 16 + mrow][q8];
        }
#pragma unroll
        for (int i = 0; i < 4; i++)
#pragma unroll
            for (int j = 0; j < 4; j++)
                acc[i][j] = __builtin_amdgcn_mfma_f32_16x16x32_bf16(af[i], bfr[j], acc[i][j], 0, 0, 0);
        __syncthreads();
    }

    int col = lane & 15, quad = lane >> 4;
    u16*  Cb = (u16*)Cv  + (outBf16 ? (long)blockIdx.z * sC : 0);
    float* Cf = (float*)Cv + (outBf16 ? 0 : (long)blockIdx.z * sC);
#pragma unroll
    for (int i = 0; i < 4; i++)
#pragma unroll
        for (int j = 0; j < 4; j++) {
#pragma unroll
            for (int rr = 0; rr < 4; rr++) {
                int gm = m0 + wm + i * 16 + quad * 4 + rr;
                int gn = n0 + wn + j * 16 + col;
                float v = acc[i][j][rr] * alpha;
                if (bias) v += bias[gn];
                if (pe)   v += pe[(long)(gm & 511) * 512 + gn];
                if (outBf16) Cb[(long)gm * ldc + gn] = f2b(v);
                else         Cf[(long)gm * ldc + gn] = v;
            }
        }
}

// ---------------------------------------------------------------------------
// Softmax over QUERY axis fp32 -> bf16
// ---------------------------------------------------------------------------
__global__ __launch_bounds__(64) void softmax_q(const float* __restrict__ S,
                                                u16* __restrict__ P) {
    int b = blockIdx.x;
    int k = blockIdx.y * 64 + threadIdx.x;
    const float* p = S + (long)b * 262144 + k;
    u16* o = P + (long)b * 262144 + k;
    float m = -1e30f;
    for (int q = 0; q < 512; q++) m = fmaxf(m, p[(long)q * 512]);
    float sum = 0.f;
    for (int q = 0; q < 512; q++) sum += expf(p[(long)q * 512] - m);
    float inv = 1.f / sum;
    for (int q = 0; q < 512; q++) o[(long)q * 512] = f2b(expf(p[(long)q * 512] - m) * inv);
}

// ---------------------------------------------------------------------------
// Zero-sync batch-parallel GRU segment.
// Grid 32 blocks x 512 threads; block owns batches {2*blk, 2*blk+1}.
// Thread t owns unit t: computes all 3 gate dot products (coalesced WT4
// loads, LDS-broadcast h), applies gates, updates h[t]. One __syncthreads
// per step; NO inter-block communication, NO device fences.
// WT4: [128 k4][1536 j][4 kk] fp32. h persists in LDS across the segment;
// hbuf carries h between segments.
// ---------------------------------------------------------------------------
__global__ __launch_bounds__(512) void gru_batch(
    const float* __restrict__ gi,     // [nsteps][64][1536] fp32 (includes bi)
    const float* __restrict__ WT4,    // [128][1536][4] fp32
    const float* __restrict__ bh_l,   // [1536]
    u16* __restrict__ seq_out,        // rows (s0+sl)*64+b, 512 cols bf16
    float* __restrict__ hbuf,         // [64][512] fp32 persistent
    int s0, int nsteps)
{
    __shared__ float h[2][2][512];    // [buf][batch-local][unit]
    int t  = threadIdx.x;
    int b0 = blockIdx.x * 2;

    if (s0 == 0) {
        h[0][0][t] = 0.f;
        h[0][1][t] = 0.f;
    } else {
        h[0][0][t] = hbuf[(long)b0 * 512 + t];
        h[0][1][t] = hbuf[(long)(b0 + 1) * 512 + t];
    }
    __syncthreads();

    float bhr = bh_l[t], bhz = bh_l[512 + t], bhn = bh_l[1024 + t];

    const float4* wr = (const float4*)WT4 + t;           // + k4*1536 per iter
    const float4* wz = wr + 512;
    const float4* wn = wr + 1024;

    for (int sl = 0; sl < nsteps; sl++) {
        int cur = sl & 1, nxt = cur ^ 1;
        const float4* ha = (const float4*)&h[cur][0][0];
        const float4* hbv = (const float4*)&h[cur][1][0];

        float4 aR0 = {0,0,0,0}, aZ0 = {0,0,0,0}, aN0 = {0,0,0,0};
        float4 aR1 = {0,0,0,0}, aZ1 = {0,0,0,0}, aN1 = {0,0,0,0};
#pragma unroll 4
        for (int k4 = 0; k4 < 128; k4++) {
            float4 w_r = wr[(long)k4 * 1536];
            float4 w_z = wz[(long)k4 * 1536];
            float4 w_n = wn[(long)k4 * 1536];
            float4 h0 = ha[k4];
            float4 h1 = hbv[k4];
            aR0.x += w_r.x * h0.x; aR0.y += w_r.y * h0.y; aR0.z += w_r.z * h0.z; aR0.w += w_r.w * h0.w;
            aZ0.x += w_z.x * h0.x; aZ0.y += w_z.y * h0.y; aZ0.z += w_z.z * h0.z; aZ0.w += w_z.w * h0.w;
            aN0.x += w_n.x * h0.x; aN0.y += w_n.y * h0.y; aN0.z += w_n.z * h0.z; aN0.w += w_n.w * h0.w;
            aR1.x += w_r.x * h1.x; aR1.y += w_r.y * h1.y; aR1.z += w_r.z * h1.z; aR1.w += w_r.w * h1.w;
            aZ1.x += w_z.x * h1.x; aZ1.y += w_z.y * h1.y; aZ1.z += w_z.z * h1.z; aZ1.w += w_z.w * h1.w;
            aN1.x += w_n.x * h1.x; aN1.y += w_n.y * h1.y; aN1.z += w_n.z * h1.z; aN1.w += w_n.w * h1.w;
        }
        float sr0 = aR0.x + aR0.y + aR0.z + aR0.w;
        float sz0 = aZ0.x + aZ0.y + aZ0.z + aZ0.w;
        float sn0 = aN0.x + aN0.y + aN0.z + aN0.w;
        float sr1 = aR1.x + aR1.y + aR1.z + aR1.w;
        float sz1 = aZ1.x + aZ1.y + aZ1.z + aZ1.w;
        float sn1 = aN1.x + aN1.y + aN1.z + aN1.w;

        const float* g0 = gi + ((long)sl * 64 + b0) * 1536;
        const float* g1 = g0 + 1536;
        float r0 = 1.f / (1.f + expf(-(g0[t] + sr0 + bhr)));
        float z0 = 1.f / (1.f + expf(-(g0[512 + t] + sz0 + bhz)));
        float n0 = tanhf(g0[1024 + t] + r0 * (sn0 + bhn));
        float r1 = 1.f / (1.f + expf(-(g1[t] + sr1 + bhr)));
        float z1 = 1.f / (1.f + expf(-(g1[512 + t] + sz1 + bhz)));
        float n1 = tanhf(g1[1024 + t] + r1 * (sn1 + bhn));
        float hp0 = h[cur][0][t], hp1 = h[cur][1][t];
        float hn0 = (1.f - z0) * n0 + z0 * hp0;
        float hn1 = (1.f - z1) * n1 + z1 * hp1;
        h[nxt][0][t] = hn0;
        h[nxt][1][t] = hn1;
        long row = ((long)(s0 + sl) * 64 + b0) * 512;
        seq_out[row + t]       = f2b(hn0);
        seq_out[row + 512 + t] = f2b(hn1);
        __syncthreads();
    }

    int fin = nsteps & 1;
    hbuf[(long)b0 * 512 + t]       = h[fin][0][t];
    hbuf[(long)(b0 + 1) * 512 + t] = h[fin][1][t];
}

// ---------------------------------------------------------------------------
__global__ __launch_bounds__(256) void final_kernel(
    const u16* __restrict__ h2, const float* __restrict__ Wf,
    const float* __restrict__ bfin, float* __restrict__ out)
{
    int w = blockIdx.x * 4 + (threadIdx.x >> 6);
    int lane = threadIdx.x & 63;
    const u16* row = h2 + (long)w * 512;
    uint4 hv = *(const uint4*)(row + lane * 8);
    float4 w0 = *(const float4*)(Wf + lane * 8);
    float4 w1 = *(const float4*)(Wf + lane * 8 + 4);
    float sum = b2f(hv.x & 0xffffu) * w0.x + b2fh(hv.x) * w0.y
              + b2f(hv.y & 0xffffu) * w0.z + b2fh(hv.y) * w0.w
              + b2f(hv.z & 0xffffu) * w1.x + b2fh(hv.z) * w1.y
              + b2f(hv.w & 0xffffu) * w1.z + b2fh(hv.w) * w1.w;
#pragma unroll
    for (int off = 32; off > 0; off >>= 1) sum += __shfl_down(sum, off, 64);
    if (lane == 0) {
        int s = w >> 6, b = w & 63;
        out[(long)b * 512 + s] = 1.f / (1.f + expf(-(sum + bfin[0])));
    }
}

// ---------------------------------------------------------------------------
// Launcher — workspace ~172.6 MB
// ---------------------------------------------------------------------------
extern "C" void kernel_launch(void* const* d_in, const int* in_sizes, int n_in,
                              void* d_out, int out_size, void* d_ws, size_t ws_size,
                              hipStream_t stream) {
    const int*   cate  = (const int*)  d_in[0];
    const float* cont  = (const float*)d_in[1];
    const float* emb   = (const float*)d_in[4];
    const float* Wc    = (const float*)d_in[5];
    const float* bc    = (const float*)d_in[6];
    const float* Wcomb = (const float*)d_in[7];
    const float* bcomb = (const float*)d_in[8];
    const float* Wq    = (const float*)d_in[9];
    const float* Wk    = (const float*)d_in[10];
    const float* Wv    = (const float*)d_in[11];
    const float* Wi    = (const float*)d_in[12];
    const float* Wh    = (const float*)d_in[13];
    const float* bi    = (const float*)d_in[14];
    const float* bh    = (const float*)d_in[15];
    const float* Wf    = (const float*)d_in[16];
    const float* bfin  = (const float*)d_in[17];
    float* out = (float*)d_out;
    char* ws = (char*)d_ws;

    u16*   zp    = (u16*)(ws + 0);
    u16*   h2bf  = (u16*)(ws + 0);
    u16*   h1bf  = (u16*)(ws + 33554432);
    float* gi    = (float*)(ws + 67108864);   // 50.3 MB, aliases xbf
    u16*   xbf   = (u16*)(ws + 67108864);
    u16*   Qg    = (u16*)(ws + 117440512);
    u16*   Kg    = (u16*)(ws + 121634816);
    u16*   Vg    = (u16*)(ws + 125829120);
    u16*   Vt    = (u16*)(ws + 130023424);
    float* Sg    = (float*)(ws + 134217728);
    u16*   Pg    = (u16*)(ws + 142606336);
    u16*   zT    = (u16*)(ws + 146800640);
    u16*   xc    = (u16*)(ws + 150994944);
    u16*   WcombT= (u16*)(ws + 159383552);
    u16*   WqT   = (u16*)(ws + 160432128);
    u16*   WkT   = (u16*)(ws + 160956416);
    u16*   WvT   = (u16*)(ws + 161480704);
    u16*   WiB   = (u16*)(ws + 162004992);
    float* pe    = (float*)(ws + 165150720);
    float* WT4   = (float*)(ws + 166199296);  // [2][128][1536][4] fp32, 6.3 MB
    float* hbuf  = (float*)(ws + 172490752);  // [64][512] fp32

    transp_w<<<dim3(16, 8), 256, 0, stream>>>(Wcomb, WcombT, 1024, 512);
    transp_w<<<dim3(8, 8),  256, 0, stream>>>(Wq, WqT, 512, 512);
    transp_w<<<dim3(8, 8),  256, 0, stream>>>(Wk, WkT, 512, 512);
    transp_w<<<dim3(8, 8),  256, 0, stream>>>(Wv, WvT, 512, 512);
    cvt_bf16<<<6144, 256, 0, stream>>>(Wi, WiB, 2L * 1536 * 512);
    wh_transp<<<6144, 256, 0, stream>>>(Wh, WT4);
    pe_kernel<<<512, 256, 0, stream>>>(pe);

    // phase 1
    for (int g = 0; g < 8; g++) {
        embed_kernel<<<4096, 256, 0, stream>>>(cate, cont, emb, Wc, bc, xc, g * 4096);
        gemm_nt<<<dim3(4, 32, 1), 256, 0, stream>>>(
            xc, WcombT, xbf + (long)g * 4096 * 512, 1024, 1024, 1024, 512,
            0, 0, 0, bcomb, pe, 1.f, 1);
    }

    // phase 2
    for (int g = 0; g < 8; g++) {
        const u16* xg = xbf + (long)g * 8 * 512 * 512;
        gemm_nt<<<dim3(4, 32, 1), 256, 0, stream>>>(xg, WqT, Qg, 512, 512, 512, 512,
                                                    0, 0, 0, nullptr, nullptr, 1.f, 1);
        gemm_nt<<<dim3(4, 32, 1), 256, 0, stream>>>(xg, WkT, Kg, 512, 512, 512, 512,
                                                    0, 0, 0, nullptr, nullptr, 1.f, 1);
        gemm_nt<<<dim3(4, 32, 1), 256, 0, stream>>>(xg, WvT, Vg, 512, 512, 512, 512,
                                                    0, 0, 0, nullptr, nullptr, 1.f, 1);
        transp_b<<<dim3(8, 8, 8), 256, 0, stream>>>(Vg, Vt, 512, 512, 262144, 262144, 512);
        gemm_nt<<<dim3(4, 4, 8), 256, 0, stream>>>(Qg, Kg, Sg, 512, 512, 512, 512,
                                                   262144, 262144, 262144, nullptr, nullptr,
                                                   0.04419417382415922f, 0);
        softmax_q<<<dim3(8, 8), 64, 0, stream>>>(Sg, Pg);
        gemm_nt<<<dim3(4, 4, 8), 256, 0, stream>>>(Vt, Pg, zT, 512, 512, 512, 512,
                                                   262144, 262144, 262144, nullptr, nullptr,
                                                   1.f, 1);
        transp_b<<<dim3(8, 8, 8), 256, 0, stream>>>(zT, zp + (long)g * 8 * 512,
                                                    512, 512, 262144, 512, 32768);
    }

    // phase 3: GRU — zero-sync batch-parallel
    for (int l = 0; l < 2; l++) {
        const u16* Aseq = (l == 0) ? zp : h1bf;
        u16* seqOut = (l == 0) ? h1bf : h2bf;
        const u16* WiL = WiB + (long)l * 1536 * 512;
        const float* WT4L = WT4 + (long)l * 786432;
        const float* biL = bi + (long)l * 1536;
        const float* bhL = bh + (long)l * 1536;
        for (int seg = 0; seg < 4; seg++) {
            gemm_nt<<<dim3(12, 64, 1), 256, 0, stream>>>(
                Aseq + (long)seg * 128 * 64 * 512, WiL, gi, 512, 512, 512, 1536,
                0, 0, 0, biL, nullptr, 1.f, 0);
            gru_batch<<<32, 512, 0, stream>>>(gi, WT4L, bhL, seqOut, hbuf,
                                              seg * 128, 128);
        }
    }

    final_kernel<<<8192, 256, 0, stream>>>(h2bf, Wf, bfin, out);
}

// Round 8
// 10399.295 us; speedup vs baseline: 6.5261x; 2.5032x over previous
//
#include <hip/hip_runtime.h>
#include <hip/hip_bf16.h>
#include <math.h>

typedef unsigned short u16;
typedef unsigned int   u32;
typedef unsigned long long u64;
typedef __attribute__((ext_vector_type(8))) short short8;
typedef __attribute__((ext_vector_type(4))) float float4v;

#define BB 64
#define SS 512

// bf16 helpers (RNE)
__device__ __forceinline__ u16 f2b(float f) {
    u32 x = __float_as_uint(f);
    u32 r = (x + 0x7fffu + ((x >> 16) & 1u)) >> 16;
    return (u16)r;
}
__device__ __forceinline__ float b2f(u32 lo16) { return __uint_as_float(lo16 << 16); }
__device__ __forceinline__ float b2fh(u32 v)   { return __uint_as_float(v & 0xffff0000u); }

// ---------------------------------------------------------------------------
__global__ __launch_bounds__(256) void zero_kernel(float* __restrict__ p, int n) {
    int i = blockIdx.x * 256 + threadIdx.x;
    if (i < n) p[i] = 0.f;
}

// ---------------------------------------------------------------------------
__global__ __launch_bounds__(256) void pe_kernel(float* __restrict__ pe) {
    int s = blockIdx.x, j = threadIdx.x;
    float ang = (float)s * powf(10000.0f, -(2.0f * (float)j) / 512.0f);
    pe[s * 512 + 2 * j]     = sinf(ang);
    pe[s * 512 + 2 * j + 1] = cosf(ang);
}

// ---------------------------------------------------------------------------
// fp32 [R][C] -> bf16 [C][R]
// ---------------------------------------------------------------------------
__global__ __launch_bounds__(256) void transp_w(const float* __restrict__ in,
                                                u16* __restrict__ out, int R, int C) {
    __shared__ float t[64][65];
    int r0 = blockIdx.x * 64, c0 = blockIdx.y * 64;
    int tid = threadIdx.x;
    int lr = tid >> 4, lc4 = (tid & 15) * 4;
#pragma unroll
    for (int i = 0; i < 4; i++) {
        int r = lr + i * 16;
        float4 v = *(const float4*)(in + (long)(r0 + r) * C + c0 + lc4);
        t[r][lc4] = v.x; t[r][lc4 + 1] = v.y; t[r][lc4 + 2] = v.z; t[r][lc4 + 3] = v.w;
    }
    __syncthreads();
#pragma unroll
    for (int i = 0; i < 4; i++) {
        int c = lr + i * 16;
        u32 lo = (u32)f2b(t[lc4][c])     | ((u32)f2b(t[lc4 + 1][c]) << 16);
        u32 hi = (u32)f2b(t[lc4 + 2][c]) | ((u32)f2b(t[lc4 + 3][c]) << 16);
        uint2 pk; pk.x = lo; pk.y = hi;
        *(uint2*)(out + (long)(c0 + c) * R + r0 + lc4) = pk;
    }
}

// ---------------------------------------------------------------------------
__global__ __launch_bounds__(256) void cvt_bf16(const float* __restrict__ in,
                                                u16* __restrict__ out, long n) {
    long i = (long)blockIdx.x * 256 + threadIdx.x;
    if (i < n) out[i] = f2b(in[i]);
}

// ---------------------------------------------------------------------------
// Wh [2][1536][512] fp32 -> WT4 [2][128][1536][4] fp32  (k-blocked transpose)
// ---------------------------------------------------------------------------
__global__ __launch_bounds__(256) void wh_transp(const float* __restrict__ Wh,
                                                 float* __restrict__ WT4) {
    long i = (long)blockIdx.x * 256 + threadIdx.x;    // < 2*786432
    if (i >= 2L * 786432) return;
    long l = i / 786432;
    long r = i % 786432;
    int k4 = (int)(r / 6144);
    int rem = (int)(r % 6144);
    int j = rem >> 2, kk = rem & 3;
    WT4[i] = Wh[l * 786432 + (long)j * 512 + k4 * 4 + kk];
}

// ---------------------------------------------------------------------------
// bf16 [nb][R][C] -> out[b][c][r] with element strides
// ---------------------------------------------------------------------------
__global__ __launch_bounds__(256) void transp_b(const u16* __restrict__ in,
                                                u16* __restrict__ out,
                                                int R, int C, long sbin, long sb, long sc) {
    __shared__ u32 t[64][65];
    int bz = blockIdx.z;
    in += (long)bz * sbin;
    int r0 = blockIdx.x * 64, c0 = blockIdx.y * 64;
    int tid = threadIdx.x;
    int lr = tid >> 4, lc4 = (tid & 15) * 4;
#pragma unroll
    for (int i = 0; i < 4; i++) {
        int r = lr + i * 16;
        uint2 v = *(const uint2*)(in + (long)(r0 + r) * C + c0 + lc4);
        t[r][lc4] = v.x & 0xffffu; t[r][lc4 + 1] = v.x >> 16;
        t[r][lc4 + 2] = v.y & 0xffffu; t[r][lc4 + 3] = v.y >> 16;
    }
    __syncthreads();
#pragma unroll
    for (int i = 0; i < 4; i++) {
        int c = lr + i * 16;
        uint2 pk;
        pk.x = t[lc4][c] | (t[lc4 + 1][c] << 16);
        pk.y = t[lc4 + 2][c] | (t[lc4 + 3][c] << 16);
        *(uint2*)(out + (long)bz * sb + (long)(c0 + c) * sc + r0 + lc4) = pk;
    }
}

// ---------------------------------------------------------------------------
__global__ __launch_bounds__(256) void embed_kernel(
    const int* __restrict__ cate, const float* __restrict__ cont,
    const float* __restrict__ emb, const float* __restrict__ Wc,
    const float* __restrict__ bc, u16* __restrict__ xc, int gbase)
{
    long bs = (long)gbase + blockIdx.x;
    long r  = blockIdx.x;
    __shared__ float cf[6];
    if (threadIdx.x < 6) cf[threadIdx.x] = cont[bs * 6 + threadIdx.x];
    __syncthreads();
    for (int h = threadIdx.x; h < 1024; h += 256) {
        float v;
        if (h < 512) {
            int c = h >> 7, e = h & 127;
            int idx = cate[bs * 4 + c];
            v = emb[((long)c * 1000 + idx) * 128 + e];
        } else {
            int hh = h - 512;
            v = bc[hh];
#pragma unroll
            for (int f = 0; f < 6; f++) v += cf[f] * Wc[f * 512 + hh];
        }
        xc[r * 1024 + h] = f2b(v);
    }
}

// ---------------------------------------------------------------------------
// bf16 MFMA NT GEMM (validated: absmax 0.0)
// ---------------------------------------------------------------------------
__global__ __launch_bounds__(256) void gemm_nt(
    const u16* __restrict__ A, const u16* __restrict__ B, void* __restrict__ Cv,
    int K, int lda, int ldb, int ldc,
    long sA, long sB, long sC,
    const float* __restrict__ bias, const float* __restrict__ pe,
    float alpha, int outBf16)
{
    __shared__ u16 As[128][40];
    __shared__ u16 Bs[128][40];

    A += (long)blockIdx.z * sA;
    B += (long)blockIdx.z * sB;
    int m0 = blockIdx.y * 128, n0 = blockIdx.x * 128;
    int tid = threadIdx.x;
    int lane = tid & 63, wid = tid >> 6;
    int wm = (wid >> 1) * 64, wn = (wid & 1) * 64;
    int mrow = lane & 15, q8 = (lane >> 4) * 8;

    float4v acc[4][4];
#pragma unroll
    for (int i = 0; i < 4; i++)
#pragma unroll
        for (int j = 0; j < 4; j++) { float4v z = {0.f, 0.f, 0.f, 0.f}; acc[i][j] = z; }

    for (int k0 = 0; k0 < K; k0 += 32) {
        {
            int r = tid >> 2, sg = tid & 3;
            *(short8*)&As[r][sg * 8] = *(const short8*)(A + (long)(m0 + r) * lda + k0 + sg * 8);
            *(short8*)&Bs[r][sg * 8] = *(const short8*)(B + (long)(n0 + r) * ldb + k0 + sg * 8);
            r = (tid + 256) >> 2;
            *(short8*)&As[r][sg * 8] = *(const short8*)(A + (long)(m0 + r) * lda + k0 + sg * 8);
            *(short8*)&Bs[r][sg * 8] = *(const short8*)(B + (long)(n0 + r) * ldb + k0 + sg * 8);
        }
        __syncthreads();
        short8 af[4], bfr[4];
#pragma unroll
        for (int t = 0; t < 4; t++) {
            af[t]  = *(const short8*)&As[wm + t * 16 + mrow][q8];
            bfr[t] = *(const short8*)&Bs[wn + t * 16 + mrow][q8];
        }
#pragma unroll
        for (int i = 0; i < 4; i++)
#pragma unroll
            for (int j = 0; j < 4; j++)
                acc[i][j] = __builtin_amdgcn_mfma_f32_16x16x32_bf16(af[i], bfr[j], acc[i][j], 0, 0, 0);
        __syncthreads();
    }

    int col = lane & 15, quad = lane >> 4;
    u16*  Cb = (u16*)Cv  + (outBf16 ? (long)blockIdx.z * sC : 0);
    float* Cf = (float*)Cv + (outBf16 ? 0 : (long)blockIdx.z * sC);
#pragma unroll
    for (int i = 0; i < 4; i++)
#pragma unroll
        for (int j = 0; j < 4; j++) {
#pragma unroll
            for (int rr = 0; rr < 4; rr++) {
                int gm = m0 + wm + i * 16 + quad * 4 + rr;
                int gn = n0 + wn + j * 16 + col;
                float v = acc[i][j][rr] * alpha;
                if (bias) v += bias[gn];
                if (pe)   v += pe[(long)(gm & 511) * 512 + gn];
                if (outBf16) Cb[(long)gm * ldc + gn] = f2b(v);
                else         Cf[(long)gm * ldc + gn] = v;
            }
        }
}

// ---------------------------------------------------------------------------
// Softmax over QUERY axis fp32 -> bf16
// ---------------------------------------------------------------------------
__global__ __launch_bounds__(64) void softmax_q(const float* __restrict__ S,
                                                u16* __restrict__ P) {
    int b = blockIdx.x;
    int k = blockIdx.y * 64 + threadIdx.x;
    const float* p = S + (long)b * 262144 + k;
    u16* o = P + (long)b * 262144 + k;
    float m = -1e30f;
    for (int q = 0; q < 512; q++) m = fmaxf(m, p[(long)q * 512]);
    float sum = 0.f;
    for (int q = 0; q < 512; q++) sum += expf(p[(long)q * 512] - m);
    float inv = 1.f / sum;
    for (int q = 0; q < 512; q++) o[(long)q * 512] = f2b(expf(p[(long)q * 512] - m) * inv);
}

// ---------------------------------------------------------------------------
// Unit-split cooperative GRU with fence-free tagged-atomic h exchange.
// Grid 256 = 32 batch-pairs x 8 unit-slices (64 units/gate each).
// Per step: each block reads only its 384KB weight slice (8x less than
// batch-only split -> beats the 64B/clk/CU L1 ceiling bottleneck).
// h exchanged via u64 {tag,f32} relaxed atomic RMWs (home-L2 coherent, NO
// fences -> no L2 invalidation storms). Parity double-buffer prevents
// overwrite races (bounded skew). Numerics: fp32 weights + fp32 h (exact).
// ---------------------------------------------------------------------------
__global__ __launch_bounds__(256, 1) void gru_ex(
    const float* __restrict__ gi,     // [128][64][1536] fp32 (includes bi)
    const float* __restrict__ WT4,    // [128 k4][1536 j][4 kk] fp32 (this layer)
    const float* __restrict__ bh_l,   // [1536]
    u16* __restrict__ seq_out,        // [512*64][512] bf16 (this layer)
    u64* __restrict__ hx,             // [2 parity][32 pair][512 unit][2 batch]
    int s0, int layer)
{
    __shared__ float hl[2][512];              // [batch-local][unit] fp32
    __shared__ float psum[4][3][2][64];       // [q][gate][batch][unit]

    int blk = blockIdx.x;
    int p   = blk >> 3;           // batch pair 0..31
    int sli = blk & 7;            // unit slice 0..7
    int ub  = sli * 64;
    int tid = threadIdx.x;
    int tu  = tid & 63;           // unit within slice
    int q   = tid >> 6;           // k-quarter 0..3
    int b0  = p * 2;

    int fu = tid & 63, fb = (tid >> 6) & 1;   // finalize mapping (tid<128)
    float bhv0 = 0.f, bhv1 = 0.f, bhv2 = 0.f;
    if (tid < 128) {
        bhv0 = bh_l[ub + fu];
        bhv1 = bh_l[512 + ub + fu];
        bhv2 = bh_l[1024 + ub + fu];
    }

    const float4* wbase = (const float4*)WT4;

    for (int sl = 0; sl < 128; sl++) {
        int s = s0 + sl;                      // layer-local step

        // ---- gather h (or zero-init at layer start) ----
        if (s == 0) {
            for (int i = tid; i < 1024; i += 256) ((float*)hl)[i] = 0.f;
        } else {
            u32 exp_tag = (u32)(layer * 512 + s);
            u64* slot = hx + (u64)(exp_tag & 1) * 32768;
            int i0 = tid, i1 = tid + 256, i2 = tid + 512, i3 = tid + 768;
            u64* p0 = slot + ((long)p * 512 + (i0 >> 1)) * 2 + (i0 & 1);
            u64* p1 = slot + ((long)p * 512 + (i1 >> 1)) * 2 + (i1 & 1);
            u64* p2 = slot + ((long)p * 512 + (i2 >> 1)) * 2 + (i2 & 1);
            u64* p3 = slot + ((long)p * 512 + (i3 >> 1)) * 2 + (i3 & 1);
            int need = 0xF;
            while (need) {
                if (need & 1) {
                    u64 v = __hip_atomic_fetch_add(p0, 0ull, __ATOMIC_RELAXED, __HIP_MEMORY_SCOPE_AGENT);
                    if ((u32)(v >> 32) == exp_tag) { hl[i0 & 1][i0 >> 1] = __uint_as_float((u32)v); need &= ~1; }
                }
                if (need & 2) {
                    u64 v = __hip_atomic_fetch_add(p1, 0ull, __ATOMIC_RELAXED, __HIP_MEMORY_SCOPE_AGENT);
                    if ((u32)(v >> 32) == exp_tag) { hl[i1 & 1][i1 >> 1] = __uint_as_float((u32)v); need &= ~2; }
                }
                if (need & 4) {
                    u64 v = __hip_atomic_fetch_add(p2, 0ull, __ATOMIC_RELAXED, __HIP_MEMORY_SCOPE_AGENT);
                    if ((u32)(v >> 32) == exp_tag) { hl[i2 & 1][i2 >> 1] = __uint_as_float((u32)v); need &= ~4; }
                }
                if (need & 8) {
                    u64 v = __hip_atomic_fetch_add(p3, 0ull, __ATOMIC_RELAXED, __HIP_MEMORY_SCOPE_AGENT);
                    if ((u32)(v >> 32) == exp_tag) { hl[i3 & 1][i3 >> 1] = __uint_as_float((u32)v); need &= ~8; }
                }
                if (need) __builtin_amdgcn_s_sleep(1);
            }
        }
        __syncthreads();

        // ---- matvec partials: this thread = (unit tu, k-quarter q) ----
        float a00 = 0.f, a01 = 0.f, a10 = 0.f, a11 = 0.f, a20 = 0.f, a21 = 0.f;
        const float4* h0v = (const float4*)hl[0] + q * 32;
        const float4* h1v = (const float4*)hl[1] + q * 32;
        const float4* w0 = wbase + (long)(q * 32) * 1536 + (ub + tu);
        const float4* w1 = w0 + 512;
        const float4* w2 = w0 + 1024;
#pragma unroll 8
        for (int k = 0; k < 32; k++) {
            float4 wv0 = w0[(long)k * 1536];
            float4 wv1 = w1[(long)k * 1536];
            float4 wv2 = w2[(long)k * 1536];
            float4 hv0 = h0v[k];
            float4 hv1 = h1v[k];
            a00 += wv0.x*hv0.x + wv0.y*hv0.y + wv0.z*hv0.z + wv0.w*hv0.w;
            a01 += wv0.x*hv1.x + wv0.y*hv1.y + wv0.z*hv1.z + wv0.w*hv1.w;
            a10 += wv1.x*hv0.x + wv1.y*hv0.y + wv1.z*hv0.z + wv1.w*hv0.w;
            a11 += wv1.x*hv1.x + wv1.y*hv1.y + wv1.z*hv1.z + wv1.w*hv1.w;
            a20 += wv2.x*hv0.x + wv2.y*hv0.y + wv2.z*hv0.z + wv2.w*hv0.w;
            a21 += wv2.x*hv1.x + wv2.y*hv1.y + wv2.z*hv1.z + wv2.w*hv1.w;
        }
        psum[q][0][0][tu] = a00;  psum[q][0][1][tu] = a01;
        psum[q][1][0][tu] = a10;  psum[q][1][1][tu] = a11;
        psum[q][2][0][tu] = a20;  psum[q][2][1][tu] = a21;
        __syncthreads();

        // ---- finalize on 128 threads ----
        if (tid < 128) {
            float sr = psum[0][0][fb][fu] + psum[1][0][fb][fu] + psum[2][0][fb][fu] + psum[3][0][fb][fu];
            float sz = psum[0][1][fb][fu] + psum[1][1][fb][fu] + psum[2][1][fb][fu] + psum[3][1][fb][fu];
            float sn = psum[0][2][fb][fu] + psum[1][2][fb][fu] + psum[2][2][fb][fu] + psum[3][2][fb][fu];
            const float* g = gi + ((long)sl * 64 + b0 + fb) * 1536;
            float ir = g[ub + fu], iz = g[512 + ub + fu], inn = g[1024 + ub + fu];
            float r  = 1.f / (1.f + expf(-(ir + sr + bhv0)));
            float zg = 1.f / (1.f + expf(-(iz + sz + bhv1)));
            float n  = tanhf(inn + r * (sn + bhv2));
            float hp = hl[fb][ub + fu];
            float hn = (1.f - zg) * n + zg * hp;
            u32 wt = (u32)(layer * 512 + s + 1);
            u64 pv = ((u64)wt << 32) | (u64)__float_as_uint(hn);
            u64* dst = hx + (u64)(wt & 1) * 32768 + ((long)p * 512 + ub + fu) * 2 + fb;
            __hip_atomic_exchange(dst, pv, __ATOMIC_RELAXED, __HIP_MEMORY_SCOPE_AGENT);
            seq_out[((long)s * 64 + b0 + fb) * 512 + ub + fu] = f2b(hn);
        }
        __syncthreads();   // protect hl/psum before next iteration overwrites
    }
}

// ---------------------------------------------------------------------------
__global__ __launch_bounds__(256) void final_kernel(
    const u16* __restrict__ h2, const float* __restrict__ Wf,
    const float* __restrict__ bfin, float* __restrict__ out)
{
    int w = blockIdx.x * 4 + (threadIdx.x >> 6);
    int lane = threadIdx.x & 63;
    const u16* row = h2 + (long)w * 512;
    uint4 hv = *(const uint4*)(row + lane * 8);
    float4 w0 = *(const float4*)(Wf + lane * 8);
    float4 w1 = *(const float4*)(Wf + lane * 8 + 4);
    float sum = b2f(hv.x & 0xffffu) * w0.x + b2fh(hv.x) * w0.y
              + b2f(hv.y & 0xffffu) * w0.z + b2fh(hv.y) * w0.w
              + b2f(hv.z & 0xffffu) * w1.x + b2fh(hv.z) * w1.y
              + b2f(hv.w & 0xffffu) * w1.z + b2fh(hv.w) * w1.w;
#pragma unroll
    for (int off = 32; off > 0; off >>= 1) sum += __shfl_down(sum, off, 64);
    if (lane == 0) {
        int s = w >> 6, b = w & 63;
        out[(long)b * 512 + s] = 1.f / (1.f + expf(-(sum + bfin[0])));
    }
}

// ---------------------------------------------------------------------------
// Launcher — workspace ~172.6 MB (hx aliases dead Sg region)
// ---------------------------------------------------------------------------
extern "C" void kernel_launch(void* const* d_in, const int* in_sizes, int n_in,
                              void* d_out, int out_size, void* d_ws, size_t ws_size,
                              hipStream_t stream) {
    const int*   cate  = (const int*)  d_in[0];
    const float* cont  = (const float*)d_in[1];
    const float* emb   = (const float*)d_in[4];
    const float* Wc    = (const float*)d_in[5];
    const float* bc    = (const float*)d_in[6];
    const float* Wcomb = (const float*)d_in[7];
    const float* bcomb = (const float*)d_in[8];
    const float* Wq    = (const float*)d_in[9];
    const float* Wk    = (const float*)d_in[10];
    const float* Wv    = (const float*)d_in[11];
    const float* Wi    = (const float*)d_in[12];
    const float* Wh    = (const float*)d_in[13];
    const float* bi    = (const float*)d_in[14];
    const float* bh    = (const float*)d_in[15];
    const float* Wf    = (const float*)d_in[16];
    const float* bfin  = (const float*)d_in[17];
    float* out = (float*)d_out;
    char* ws = (char*)d_ws;

    u16*   zp    = (u16*)(ws + 0);
    u16*   h2bf  = (u16*)(ws + 0);
    u16*   h1bf  = (u16*)(ws + 33554432);
    float* gi    = (float*)(ws + 67108864);   // 50.3 MB, aliases xbf
    u16*   xbf   = (u16*)(ws + 67108864);
    u16*   Qg    = (u16*)(ws + 117440512);
    u16*   Kg    = (u16*)(ws + 121634816);
    u16*   Vg    = (u16*)(ws + 125829120);
    u16*   Vt    = (u16*)(ws + 130023424);
    float* Sg    = (float*)(ws + 134217728);  // phase-2 only
    u64*   hx    = (u64*)  (ws + 134217728);  // 1 MB, aliases dead Sg (phase 3)
    u16*   Pg    = (u16*)(ws + 142606336);
    u16*   zT    = (u16*)(ws + 146800640);
    u16*   xc    = (u16*)(ws + 150994944);
    u16*   WcombT= (u16*)(ws + 159383552);
    u16*   WqT   = (u16*)(ws + 160432128);
    u16*   WkT   = (u16*)(ws + 160956416);
    u16*   WvT   = (u16*)(ws + 161480704);
    u16*   WiB   = (u16*)(ws + 162004992);
    float* pe    = (float*)(ws + 165150720);
    float* WT4   = (float*)(ws + 166199296);  // [2][128][1536][4] fp32, 6.3 MB

    transp_w<<<dim3(16, 8), 256, 0, stream>>>(Wcomb, WcombT, 1024, 512);
    transp_w<<<dim3(8, 8),  256, 0, stream>>>(Wq, WqT, 512, 512);
    transp_w<<<dim3(8, 8),  256, 0, stream>>>(Wk, WkT, 512, 512);
    transp_w<<<dim3(8, 8),  256, 0, stream>>>(Wv, WvT, 512, 512);
    cvt_bf16<<<6144, 256, 0, stream>>>(Wi, WiB, 2L * 1536 * 512);
    wh_transp<<<6144, 256, 0, stream>>>(Wh, WT4);
    pe_kernel<<<512, 256, 0, stream>>>(pe);

    // phase 1
    for (int g = 0; g < 8; g++) {
        embed_kernel<<<4096, 256, 0, stream>>>(cate, cont, emb, Wc, bc, xc, g * 4096);
        gemm_nt<<<dim3(4, 32, 1), 256, 0, stream>>>(
            xc, WcombT, xbf + (long)g * 4096 * 512, 1024, 1024, 1024, 512,
            0, 0, 0, bcomb, pe, 1.f, 1);
    }

    // phase 2
    for (int g = 0; g < 8; g++) {
        const u16* xg = xbf + (long)g * 8 * 512 * 512;
        gemm_nt<<<dim3(4, 32, 1), 256, 0, stream>>>(xg, WqT, Qg, 512, 512, 512, 512,
                                                    0, 0, 0, nullptr, nullptr, 1.f, 1);
        gemm_nt<<<dim3(4, 32, 1), 256, 0, stream>>>(xg, WkT, Kg, 512, 512, 512, 512,
                                                    0, 0, 0, nullptr, nullptr, 1.f, 1);
        gemm_nt<<<dim3(4, 32, 1), 256, 0, stream>>>(xg, WvT, Vg, 512, 512, 512, 512,
                                                    0, 0, 0, nullptr, nullptr, 1.f, 1);
        transp_b<<<dim3(8, 8, 8), 256, 0, stream>>>(Vg, Vt, 512, 512, 262144, 262144, 512);
        gemm_nt<<<dim3(4, 4, 8), 256, 0, stream>>>(Qg, Kg, Sg, 512, 512, 512, 512,
                                                   262144, 262144, 262144, nullptr, nullptr,
                                                   0.04419417382415922f, 0);
        softmax_q<<<dim3(8, 8), 64, 0, stream>>>(Sg, Pg);
        gemm_nt<<<dim3(4, 4, 8), 256, 0, stream>>>(Vt, Pg, zT, 512, 512, 512, 512,
                                                   262144, 262144, 262144, nullptr, nullptr,
                                                   1.f, 1);
        transp_b<<<dim3(8, 8, 8), 256, 0, stream>>>(zT, zp + (long)g * 8 * 512,
                                                    512, 512, 262144, 512, 32768);
    }

    // phase 3: GRU — unit-split cooperative with tagged-atomic exchange
    zero_kernel<<<1024, 256, 0, stream>>>((float*)hx, 262144);  // 1 MB hx
    for (int l = 0; l < 2; l++) {
        const u16* Aseq = (l == 0) ? zp : h1bf;
        u16* seqOut = (l == 0) ? h1bf : h2bf;
        const u16* WiL = WiB + (long)l * 1536 * 512;
        const float* WT4L = WT4 + (long)l * 786432;
        const float* biL = bi + (long)l * 1536;
        const float* bhL = bh + (long)l * 1536;
        for (int seg = 0; seg < 4; seg++) {
            gemm_nt<<<dim3(12, 64, 1), 256, 0, stream>>>(
                Aseq + (long)seg * 128 * 64 * 512, WiL, gi, 512, 512, 512, 1536,
                0, 0, 0, biL, nullptr, 1.f, 0);
            const float* giP = gi;
            u16* soP = seqOut;
            int s0v = seg * 128;
            int lv = l;
            void* args[] = { (void*)&giP, (void*)&WT4L, (void*)&bhL, (void*)&soP,
                             (void*)&hx, (void*)&s0v, (void*)&lv };
            hipLaunchCooperativeKernel((void*)gru_ex, dim3(256), dim3(256),
                                       args, 0, stream);
        }
    }

    final_kernel<<<8192, 256, 0, stream>>>(h2bf, Wf, bfin, out);
}